// Round 1
// baseline (1976.567 us; speedup 1.0000x reference)
//
#include <hip/hip_runtime.h>
#include <hip/hip_bf16.h>
#include <cfloat>

#define NN_TOTAL 32768   // 8 * 4096 rows
#define NPTS     4096

// ======================= tiled fp32 GEMM + bias + optional ELU =======================
// C[M][N] = A[M][K] @ W[K][N] + bias ; act=1 -> ELU
// BM=BN=128, BK=8, 256 threads, 8x8 microtile per thread. M must be multiple of 128.
__global__ __launch_bounds__(256) void gemm_bias_act(
    const float* __restrict__ A, const float* __restrict__ W,
    const float* __restrict__ bias, float* __restrict__ C,
    int N, int K, int lda, int ldc, int act)
{
    __shared__ float As[8][128];
    __shared__ float Bs[8][128];
    const int tid  = threadIdx.x;
    const int row0 = blockIdx.x * 128;
    const int col0 = blockIdx.y * 128;
    const int tx = tid & 15;        // 16 col-groups
    const int ty = tid >> 4;        // 16 row-groups
    const int crow = ty * 8;
    const int ccol = tx * 8;

    float acc[8][8];
    #pragma unroll
    for (int i = 0; i < 8; i++)
        #pragma unroll
        for (int j = 0; j < 8; j++) acc[i][j] = 0.f;

    for (int k0 = 0; k0 < K; k0 += 8) {
        // ---- stage A tile: 128 rows x 8 k, thread t -> row t/2, k-quad t%2
        {
            const int m  = tid >> 1;
            const int kq = (tid & 1) * 4;
            const int gm = row0 + m;
            const float* ap = A + (size_t)gm * lda + k0 + kq;
            float t0, t1, t2, t3;
            t0 = (k0 + kq + 0 < K) ? ap[0] : 0.f;
            t1 = (k0 + kq + 1 < K) ? ap[1] : 0.f;
            t2 = (k0 + kq + 2 < K) ? ap[2] : 0.f;
            t3 = (k0 + kq + 3 < K) ? ap[3] : 0.f;
            As[kq + 0][m] = t0;
            As[kq + 1][m] = t1;
            As[kq + 2][m] = t2;
            As[kq + 3][m] = t3;
        }
        // ---- stage B tile: 8 k x 128 n, thread t -> k t/32, n-quad t%32
        {
            const int kk = tid >> 5;
            const int n  = (tid & 31) * 4;
            const int gk = k0 + kk;
            const int gn = col0 + n;
            float4 v = make_float4(0.f, 0.f, 0.f, 0.f);
            if (gk < K) {
                const float* bp = W + (size_t)gk * N + gn;
                v.x = (gn + 0 < N) ? bp[0] : 0.f;
                v.y = (gn + 1 < N) ? bp[1] : 0.f;
                v.z = (gn + 2 < N) ? bp[2] : 0.f;
                v.w = (gn + 3 < N) ? bp[3] : 0.f;
            }
            *(float4*)&Bs[kk][n] = v;
        }
        __syncthreads();

        #pragma unroll
        for (int k = 0; k < 8; k++) {
            float a[8], b[8];
            *(float4*)&a[0] = *(float4*)&As[k][crow];
            *(float4*)&a[4] = *(float4*)&As[k][crow + 4];
            *(float4*)&b[0] = *(float4*)&Bs[k][ccol];
            *(float4*)&b[4] = *(float4*)&Bs[k][ccol + 4];
            #pragma unroll
            for (int i = 0; i < 8; i++)
                #pragma unroll
                for (int j = 0; j < 8; j++)
                    acc[i][j] = fmaf(a[i], b[j], acc[i][j]);
        }
        __syncthreads();
    }

    // ---- epilogue
    #pragma unroll
    for (int i = 0; i < 8; i++) {
        const int gr = row0 + crow + i;
        #pragma unroll
        for (int j = 0; j < 8; j++) {
            const int gc = col0 + ccol + j;
            if (gc < N) {
                float v = acc[i][j] + bias[gc];
                if (act) v = (v > 0.f) ? v : expm1f(v);
                C[(size_t)gr * ldc + gc] = v;
            }
        }
    }
}

// ======================= GravNet: projections s,h and |s|^2 =======================
__global__ __launch_bounds__(256) void conv_proj(
    const float* __restrict__ emb, const float* __restrict__ Ws,
    const float* __restrict__ bs, const float* __restrict__ Wh,
    const float* __restrict__ bh,
    float* __restrict__ s_out, float* __restrict__ sq_out, float* __restrict__ h_out)
{
    __shared__ float ws_s[32 * 4];
    __shared__ float wh_s[32 * 8];
    __shared__ float bs_s[4];
    __shared__ float bh_s[8];
    const int tid = threadIdx.x;
    if (tid < 128) ws_s[tid] = Ws[tid];
    if (tid >= 128 && tid < 128 + 4) bs_s[tid - 128] = bs[tid - 128];
    if (tid >= 136 && tid < 136 + 8) bh_s[tid - 136] = bh[tid - 136];
    for (int i = tid; i < 256; i += 256) wh_s[i] = Wh[i];
    __syncthreads();

    const int row = blockIdx.x * 256 + tid;
    float e[32];
    #pragma unroll
    for (int i = 0; i < 8; i++)
        *(float4*)&e[i * 4] = *(const float4*)(emb + (size_t)row * 32 + i * 4);

    float sv[4];
    #pragma unroll
    for (int c = 0; c < 4; c++) {
        float a = e[0] * ws_s[c];
        #pragma unroll
        for (int k = 1; k < 32; k++) a = fmaf(e[k], ws_s[k * 4 + c], a);
        sv[c] = a + bs_s[c];
    }
    float sq = sv[0] * sv[0];
    sq = fmaf(sv[1], sv[1], sq);
    sq = fmaf(sv[2], sv[2], sq);
    sq = fmaf(sv[3], sv[3], sq);

    float hv[8];
    #pragma unroll
    for (int c = 0; c < 8; c++) {
        float a = e[0] * wh_s[c];
        #pragma unroll
        for (int k = 1; k < 32; k++) a = fmaf(e[k], wh_s[k * 8 + c], a);
        hv[c] = a + bh_s[c];
    }

    *(float4*)(s_out + (size_t)row * 4) = *(float4*)&sv[0];
    sq_out[row] = sq;
    *(float4*)(h_out + (size_t)row * 8)     = *(float4*)&hv[0];
    *(float4*)(h_out + (size_t)row * 8 + 4) = *(float4*)&hv[4];
}

// ======================= kNN top-4 (per batch of 4096 pts, S=4) =======================
#define KTILE 512
__global__ __launch_bounds__(256) void knn_top4(
    const float* __restrict__ s, const float* __restrict__ sq,
    int* __restrict__ idx_out, float* __restrict__ w_out)
{
    __shared__ float ls[KTILE][5];
    const int tid  = threadIdx.x;
    const int row  = blockIdx.x * 256 + tid;     // global point index
    const int base = (row >> 12) << 12;          // batch start row

    const float4 sn = *(const float4*)(s + (size_t)row * 4);
    const float sqn = sq[row];

    float bd[4] = {FLT_MAX, FLT_MAX, FLT_MAX, FLT_MAX};
    int   bi[4] = {-1, -1, -1, -1};

    for (int m0 = 0; m0 < NPTS; m0 += KTILE) {
        __syncthreads();
        #pragma unroll
        for (int i = tid; i < KTILE; i += 256) {
            const int gm = base + m0 + i;
            const float4 sm = *(const float4*)(s + (size_t)gm * 4);
            ls[i][0] = sm.x; ls[i][1] = sm.y; ls[i][2] = sm.z; ls[i][3] = sm.w;
            ls[i][4] = sq[gm];
        }
        __syncthreads();

        #pragma unroll 4
        for (int i = 0; i < KTILE; i++) {
            float dot = sn.x * ls[i][0];
            dot = fmaf(sn.y, ls[i][1], dot);
            dot = fmaf(sn.z, ls[i][2], dot);
            dot = fmaf(sn.w, ls[i][3], dot);
            const float d2 = (sqn + ls[i][4]) - 2.f * dot;
            const int m = m0 + i;
            if (d2 < bd[3]) {                 // strict < : stable tie-break (earlier index wins)
                bd[3] = d2; bi[3] = m;
                if (d2 < bd[2]) {
                    bd[3] = bd[2]; bi[3] = bi[2]; bd[2] = d2; bi[2] = m;
                    if (d2 < bd[1]) {
                        bd[2] = bd[1]; bi[2] = bi[1]; bd[1] = d2; bi[1] = m;
                        if (d2 < bd[0]) {
                            bd[1] = bd[0]; bi[1] = bi[0]; bd[0] = d2; bi[0] = m;
                        }
                    }
                }
            }
        }
    }

    #pragma unroll
    for (int k = 0; k < 4; k++) {
        idx_out[(size_t)row * 4 + k] = base + bi[k];                 // global gather index
        w_out[(size_t)row * 4 + k]   = expf(-10.f * fmaxf(bd[k], 0.f));
    }
}

// ======================= GravNet: aggregate + output linear =======================
__global__ __launch_bounds__(256) void conv_agg(
    const float* __restrict__ emb, const float* __restrict__ h,
    const int* __restrict__ idx, const float* __restrict__ w,
    const float* __restrict__ Wo1, const float* __restrict__ Wo2,
    const float* __restrict__ bo2, float* __restrict__ out)
{
    __shared__ float w1[32 * 32];
    __shared__ float w2[16 * 32];
    __shared__ float b2[32];
    const int tid = threadIdx.x;
    for (int i = tid; i < 1024; i += 256) w1[i] = Wo1[i];
    for (int i = tid; i < 512;  i += 256) w2[i] = Wo2[i];
    if (tid < 32) b2[tid] = bo2[tid];
    __syncthreads();

    const int row = blockIdx.x * 256 + tid;

    float e[32];
    #pragma unroll
    for (int i = 0; i < 8; i++)
        *(float4*)&e[i * 4] = *(const float4*)(emb + (size_t)row * 32 + i * 4);

    float msum[8], mmax[8];
    #pragma unroll
    for (int d = 0; d < 8; d++) { msum[d] = 0.f; mmax[d] = -FLT_MAX; }

    #pragma unroll
    for (int k = 0; k < 4; k++) {
        const int g   = idx[(size_t)row * 4 + k];
        const float wk = w[(size_t)row * 4 + k];
        float hv[8];
        *(float4*)&hv[0] = *(const float4*)(h + (size_t)g * 8);
        *(float4*)&hv[4] = *(const float4*)(h + (size_t)g * 8 + 4);
        #pragma unroll
        for (int d = 0; d < 8; d++) {
            const float m = hv[d] * wk;
            msum[d] += m;
            mmax[d] = fmaxf(mmax[d], m);
        }
    }

    float agg[16];
    #pragma unroll
    for (int d = 0; d < 8; d++) { agg[d] = msum[d] * 0.25f; agg[8 + d] = mmax[d]; }

    #pragma unroll
    for (int j = 0; j < 32; j++) {
        float a = e[0] * w1[j];
        #pragma unroll
        for (int k = 1; k < 32; k++) a = fmaf(e[k], w1[k * 32 + j], a);
        float g = agg[0] * w2[j];
        #pragma unroll
        for (int k = 1; k < 16; k++) g = fmaf(agg[k], w2[k * 32 + j], g);
        out[(size_t)row * 32 + j] = a + g + b2[j];
    }
}

// ======================= concat helpers =======================
__global__ __launch_bounds__(256) void cat2_kernel(
    const float* __restrict__ x, const float* __restrict__ emb, float* __restrict__ out)
{
    const int row = blockIdx.x * 256 + threadIdx.x;
    const float* xr = x + (size_t)row * 12;
    const float* er = emb + (size_t)row * 32;
    float* o = out + (size_t)row * 44;
    #pragma unroll
    for (int i = 0; i < 3; i++) ((float4*)o)[i] = ((const float4*)xr)[i];
    #pragma unroll
    for (int i = 0; i < 8; i++) ((float4*)(o + 12))[i] = ((const float4*)er)[i];
}

__global__ __launch_bounds__(256) void cat3_kernel(
    const float* __restrict__ x, const float* __restrict__ pid, float* __restrict__ out)
{
    const int row = blockIdx.x * 256 + threadIdx.x;
    const float* xr = x + (size_t)row * 12;
    const float* pr = pid + (size_t)row * 12;   // preds_id lives in d_out with ldc=12
    float* o = out + (size_t)row * 18;
    #pragma unroll
    for (int i = 0; i < 12; i++) o[i] = xr[i];
    #pragma unroll
    for (int i = 0; i < 6; i++) o[12 + i] = pr[i];
}

// ======================= host launcher =======================
extern "C" void kernel_launch(void* const* d_in, const int* in_sizes, int n_in,
                              void* d_out, int out_size, void* d_ws, size_t ws_size,
                              hipStream_t stream)
{
    const float* x = (const float*)d_in[0];
    const float* nn1_w[4] = {(const float*)d_in[1], (const float*)d_in[3], (const float*)d_in[5], (const float*)d_in[7]};
    const float* nn1_b[4] = {(const float*)d_in[2], (const float*)d_in[4], (const float*)d_in[6], (const float*)d_in[8]};
    const float* nn2_w[4] = {(const float*)d_in[9],  (const float*)d_in[11], (const float*)d_in[13], (const float*)d_in[15]};
    const float* nn2_b[4] = {(const float*)d_in[10], (const float*)d_in[12], (const float*)d_in[14], (const float*)d_in[16]};
    const float* nn3_w[4] = {(const float*)d_in[17], (const float*)d_in[19], (const float*)d_in[21], (const float*)d_in[23]};
    const float* nn3_b[4] = {(const float*)d_in[18], (const float*)d_in[20], (const float*)d_in[22], (const float*)d_in[24]};
    const float* conv_ws  = (const float*)d_in[25];  // [3,32,4]
    const float* conv_bs  = (const float*)d_in[26];  // [3,4]
    const float* conv_wh  = (const float*)d_in[27];  // [3,32,8]
    const float* conv_bh  = (const float*)d_in[28];  // [3,8]
    const float* conv_wo1 = (const float*)d_in[29];  // [3,32,32]
    const float* conv_wo2 = (const float*)d_in[30];  // [3,16,32]
    const float* conv_bo2 = (const float*)d_in[31];  // [3,32]

    float* outp = (float*)d_out;

    // workspace partition
    char* p = (char*)d_ws;
    auto take = [&](size_t bytes) { char* r = p; p += (bytes + 255) & ~size_t(255); return r; };
    float* bufA = (float*)take((size_t)NN_TOTAL * 256 * 4);
    float* bufB = (float*)take((size_t)NN_TOTAL * 256 * 4);
    float* embA = (float*)take((size_t)NN_TOTAL * 32 * 4);
    float* embB = (float*)take((size_t)NN_TOTAL * 32 * 4);
    float* sbuf = (float*)take((size_t)NN_TOTAL * 4 * 4);
    float* sqb  = (float*)take((size_t)NN_TOTAL * 4);
    float* hbuf = (float*)take((size_t)NN_TOTAL * 8 * 4);
    int*   idxb = (int*)take((size_t)NN_TOTAL * 4 * 4);
    float* wbuf = (float*)take((size_t)NN_TOTAL * 4 * 4);

    auto gemm = [&](const float* A, const float* W, const float* b, float* C,
                    int N, int K, int lda, int ldc, int act) {
        dim3 g(NN_TOTAL / 128, (N + 127) / 128);
        gemm_bias_act<<<g, 256, 0, stream>>>(A, W, b, C, N, K, lda, ldc, act);
    };

    // ---- nn1 MLP: 12 -> 126 -> 126 -> 126 -> 32
    gemm(x,    nn1_w[0], nn1_b[0], bufA, 126, 12,  12,  126, 1);
    gemm(bufA, nn1_w[1], nn1_b[1], bufB, 126, 126, 126, 126, 1);
    gemm(bufB, nn1_w[2], nn1_b[2], bufA, 126, 126, 126, 126, 1);
    gemm(bufA, nn1_w[3], nn1_b[3], embA, 32,  126, 126, 32,  0);

    // ---- 3 GravNet convs
    float* ecur = embA;
    float* enext = embB;
    for (int i = 0; i < 3; i++) {
        conv_proj<<<NN_TOTAL / 256, 256, 0, stream>>>(
            ecur, conv_ws + i * 128, conv_bs + i * 4, conv_wh + i * 256, conv_bh + i * 8,
            sbuf, sqb, hbuf);
        knn_top4<<<NN_TOTAL / 256, 256, 0, stream>>>(sbuf, sqb, idxb, wbuf);
        conv_agg<<<NN_TOTAL / 256, 256, 0, stream>>>(
            ecur, hbuf, idxb, wbuf,
            conv_wo1 + i * 1024, conv_wo2 + i * 512, conv_bo2 + i * 32, enext);
        float* t = ecur; ecur = enext; enext = t;
    }
    // ecur == final emb

    // ---- nn2 MLP: concat(x, emb)=44 -> 256 -> 256 -> 256 -> 6  (writes d_out cols 0..5)
    cat2_kernel<<<NN_TOTAL / 256, 256, 0, stream>>>(x, ecur, bufA);
    gemm(bufA, nn2_w[0], nn2_b[0], bufB, 256, 44,  44,  256, 1);
    gemm(bufB, nn2_w[1], nn2_b[1], bufA, 256, 256, 256, 256, 1);
    gemm(bufA, nn2_w[2], nn2_b[2], bufB, 256, 256, 256, 256, 1);
    gemm(bufB, nn2_w[3], nn2_b[3], outp, 6,   256, 256, 12,  0);

    // ---- nn3 MLP: concat(x, preds_id)=18 -> 256 -> 256 -> 256 -> 6 (writes d_out cols 6..11)
    cat3_kernel<<<NN_TOTAL / 256, 256, 0, stream>>>(x, outp, bufA);
    gemm(bufA, nn3_w[0], nn3_b[0], bufB, 256, 18,  18,  256, 1);
    gemm(bufB, nn3_w[1], nn3_b[1], bufA, 256, 256, 256, 256, 1);
    gemm(bufA, nn3_w[2], nn3_b[2], bufB, 256, 256, 256, 256, 1);
    gemm(bufB, nn3_w[3], nn3_b[3], outp + 6, 6, 256, 256, 12, 0);
}

// Round 2
// 1199.196 us; speedup vs baseline: 1.6482x; 1.6482x over previous
//
#include <hip/hip_runtime.h>
#include <hip/hip_bf16.h>
#include <cfloat>
#include <climits>

#define NN_TOTAL 32768   // 8 * 4096 rows
#define NPTS     4096

// ======================= tiled fp32 GEMM + bias + optional ELU =======================
// C[M][N] = A[M][K] @ W[K][N] + bias ; act=1 -> ELU
// BM=BN=128, BK=8, 256 threads, 8x8 microtile per thread. M must be multiple of 128.
__global__ __launch_bounds__(256) void gemm_bias_act(
    const float* __restrict__ A, const float* __restrict__ W,
    const float* __restrict__ bias, float* __restrict__ C,
    int N, int K, int lda, int ldc, int act)
{
    __shared__ float As[8][128];
    __shared__ float Bs[8][128];
    const int tid  = threadIdx.x;
    const int row0 = blockIdx.x * 128;
    const int col0 = blockIdx.y * 128;
    const int tx = tid & 15;        // 16 col-groups
    const int ty = tid >> 4;        // 16 row-groups
    const int crow = ty * 8;
    const int ccol = tx * 8;

    float acc[8][8];
    #pragma unroll
    for (int i = 0; i < 8; i++)
        #pragma unroll
        for (int j = 0; j < 8; j++) acc[i][j] = 0.f;

    for (int k0 = 0; k0 < K; k0 += 8) {
        // ---- stage A tile: 128 rows x 8 k, thread t -> row t/2, k-quad t%2
        {
            const int m  = tid >> 1;
            const int kq = (tid & 1) * 4;
            const int gm = row0 + m;
            const float* ap = A + (size_t)gm * lda + k0 + kq;
            float t0, t1, t2, t3;
            t0 = (k0 + kq + 0 < K) ? ap[0] : 0.f;
            t1 = (k0 + kq + 1 < K) ? ap[1] : 0.f;
            t2 = (k0 + kq + 2 < K) ? ap[2] : 0.f;
            t3 = (k0 + kq + 3 < K) ? ap[3] : 0.f;
            As[kq + 0][m] = t0;
            As[kq + 1][m] = t1;
            As[kq + 2][m] = t2;
            As[kq + 3][m] = t3;
        }
        // ---- stage B tile: 8 k x 128 n, thread t -> k t/32, n-quad t%32
        {
            const int kk = tid >> 5;
            const int n  = (tid & 31) * 4;
            const int gk = k0 + kk;
            const int gn = col0 + n;
            float4 v = make_float4(0.f, 0.f, 0.f, 0.f);
            if (gk < K) {
                const float* bp = W + (size_t)gk * N + gn;
                v.x = (gn + 0 < N) ? bp[0] : 0.f;
                v.y = (gn + 1 < N) ? bp[1] : 0.f;
                v.z = (gn + 2 < N) ? bp[2] : 0.f;
                v.w = (gn + 3 < N) ? bp[3] : 0.f;
            }
            *(float4*)&Bs[kk][n] = v;
        }
        __syncthreads();

        #pragma unroll
        for (int k = 0; k < 8; k++) {
            float a[8], b[8];
            *(float4*)&a[0] = *(float4*)&As[k][crow];
            *(float4*)&a[4] = *(float4*)&As[k][crow + 4];
            *(float4*)&b[0] = *(float4*)&Bs[k][ccol];
            *(float4*)&b[4] = *(float4*)&Bs[k][ccol + 4];
            #pragma unroll
            for (int i = 0; i < 8; i++)
                #pragma unroll
                for (int j = 0; j < 8; j++)
                    acc[i][j] = fmaf(a[i], b[j], acc[i][j]);
        }
        __syncthreads();
    }

    // ---- epilogue
    #pragma unroll
    for (int i = 0; i < 8; i++) {
        const int gr = row0 + crow + i;
        #pragma unroll
        for (int j = 0; j < 8; j++) {
            const int gc = col0 + ccol + j;
            if (gc < N) {
                float v = acc[i][j] + bias[gc];
                if (act) v = (v > 0.f) ? v : expm1f(v);
                C[(size_t)gr * ldc + gc] = v;
            }
        }
    }
}

// ======================= GravNet: projections s,h and |s|^2 =======================
__global__ __launch_bounds__(256) void conv_proj(
    const float* __restrict__ emb, const float* __restrict__ Ws,
    const float* __restrict__ bs, const float* __restrict__ Wh,
    const float* __restrict__ bh,
    float* __restrict__ s_out, float* __restrict__ sq_out, float* __restrict__ h_out)
{
    __shared__ float ws_s[32 * 4];
    __shared__ float wh_s[32 * 8];
    __shared__ float bs_s[4];
    __shared__ float bh_s[8];
    const int tid = threadIdx.x;
    if (tid < 128) ws_s[tid] = Ws[tid];
    if (tid >= 128 && tid < 128 + 4) bs_s[tid - 128] = bs[tid - 128];
    if (tid >= 136 && tid < 136 + 8) bh_s[tid - 136] = bh[tid - 136];
    for (int i = tid; i < 256; i += 256) wh_s[i] = Wh[i];
    __syncthreads();

    const int row = blockIdx.x * 256 + tid;
    float e[32];
    #pragma unroll
    for (int i = 0; i < 8; i++)
        *(float4*)&e[i * 4] = *(const float4*)(emb + (size_t)row * 32 + i * 4);

    float sv[4];
    #pragma unroll
    for (int c = 0; c < 4; c++) {
        float a = e[0] * ws_s[c];
        #pragma unroll
        for (int k = 1; k < 32; k++) a = fmaf(e[k], ws_s[k * 4 + c], a);
        sv[c] = a + bs_s[c];
    }
    float sq = sv[0] * sv[0];
    sq = fmaf(sv[1], sv[1], sq);
    sq = fmaf(sv[2], sv[2], sq);
    sq = fmaf(sv[3], sv[3], sq);

    float hv[8];
    #pragma unroll
    for (int c = 0; c < 8; c++) {
        float a = e[0] * wh_s[c];
        #pragma unroll
        for (int k = 1; k < 32; k++) a = fmaf(e[k], wh_s[k * 8 + c], a);
        hv[c] = a + bh_s[c];
    }

    *(float4*)(s_out + (size_t)row * 4) = *(float4*)&sv[0];
    sq_out[row] = sq;
    *(float4*)(h_out + (size_t)row * 8)     = *(float4*)&hv[0];
    *(float4*)(h_out + (size_t)row * 8 + 4) = *(float4*)&hv[4];
}

// ======================= kNN top-4 v2 =======================
// Block = 64 points, 256 threads = 4 waves. Wave w handles candidate quarter
// [t*1024 + w*256, +256) for ALL 64 points (lane = point -> LDS broadcast).
// Per-wave sorted top-4 in registers, then 4-way merge per point via LDS with
// lexicographic (d2, idx) compare == lax.top_k stable tie-break.
__device__ __forceinline__ void merge44(const float* ad, const int* ai,
                                        const float* bd, const int* bi,
                                        float* od, int* oi)
{
    int a = 0, b = 0;
    #pragma unroll
    for (int k = 0; k < 4; ++k) {
        bool ta;
        if (a < 4 && b < 4)
            ta = (ad[a] < bd[b]) || (ad[a] == bd[b] && ai[a] < bi[b]);
        else
            ta = (a < 4);
        if (ta) { od[k] = ad[a]; oi[k] = ai[a]; ++a; }
        else    { od[k] = bd[b]; oi[k] = bi[b]; ++b; }
    }
}

__global__ __launch_bounds__(256) void knn_top4_v2(
    const float* __restrict__ s, const float* __restrict__ sq,
    int* __restrict__ idx_out, float* __restrict__ w_out)
{
    __shared__ float4 cs[1024];
    __shared__ float  csq[1024];
    __shared__ float  md[4][64][4];
    __shared__ int    mi[4][64][4];

    const int tid  = threadIdx.x;
    const int wv   = tid >> 6;
    const int ln   = tid & 63;
    const int p0   = blockIdx.x * 64;          // first point of this block
    const int base = (p0 >> 12) << 12;         // batch base row
    const int row  = p0 + ln;                  // this lane's point

    const float4 sn  = *(const float4*)(s + (size_t)row * 4);
    const float  sqn = sq[row];

    float bd[4] = {FLT_MAX, FLT_MAX, FLT_MAX, FLT_MAX};
    int   bi[4] = {INT_MAX, INT_MAX, INT_MAX, INT_MAX};

    for (int t = 0; t < 4; ++t) {
        const int m0 = t * 1024;
        __syncthreads();
        #pragma unroll
        for (int j = tid; j < 1024; j += 256) {
            const int gm = base + m0 + j;
            cs[j]  = *(const float4*)(s + (size_t)gm * 4);
            csq[j] = sq[gm];
        }
        __syncthreads();

        const int c0 = wv * 256;
        #pragma unroll 4
        for (int i = 0; i < 256; ++i) {
            const float4 cm = cs[c0 + i];
            const float  cq = csq[c0 + i];
            float dot = sn.x * cm.x;
            dot = fmaf(sn.y, cm.y, dot);
            dot = fmaf(sn.z, cm.z, dot);
            dot = fmaf(sn.w, cm.w, dot);
            const float d2 = (sqn + cq) - 2.f * dot;
            const int m = m0 + c0 + i;
            if (d2 < bd[3]) {              // strict <: earlier index wins ties
                bd[3] = d2; bi[3] = m;
                if (d2 < bd[2]) {
                    bd[3] = bd[2]; bi[3] = bi[2]; bd[2] = d2; bi[2] = m;
                    if (d2 < bd[1]) {
                        bd[2] = bd[1]; bi[2] = bi[1]; bd[1] = d2; bi[1] = m;
                        if (d2 < bd[0]) {
                            bd[1] = bd[0]; bi[1] = bi[0]; bd[0] = d2; bi[0] = m;
                        }
                    }
                }
            }
        }
    }

    #pragma unroll
    for (int k = 0; k < 4; ++k) { md[wv][ln][k] = bd[k]; mi[wv][ln][k] = bi[k]; }
    __syncthreads();

    if (wv == 0) {
        float l0d[4], l1d[4], l2d[4], l3d[4];
        int   l0i[4], l1i[4], l2i[4], l3i[4];
        #pragma unroll
        for (int k = 0; k < 4; ++k) {
            l0d[k] = md[0][ln][k]; l0i[k] = mi[0][ln][k];
            l1d[k] = md[1][ln][k]; l1i[k] = mi[1][ln][k];
            l2d[k] = md[2][ln][k]; l2i[k] = mi[2][ln][k];
            l3d[k] = md[3][ln][k]; l3i[k] = mi[3][ln][k];
        }
        float m01d[4], m23d[4], fd[4];
        int   m01i[4], m23i[4], fi[4];
        merge44(l0d, l0i, l1d, l1i, m01d, m01i);
        merge44(l2d, l2i, l3d, l3i, m23d, m23i);
        merge44(m01d, m01i, m23d, m23i, fd, fi);

        #pragma unroll
        for (int k = 0; k < 4; ++k) {
            idx_out[(size_t)row * 4 + k] = base + fi[k];
            w_out[(size_t)row * 4 + k]   = expf(-10.f * fmaxf(fd[k], 0.f));
        }
    }
}

// ======================= GravNet: aggregate + output linear =======================
__global__ __launch_bounds__(256) void conv_agg(
    const float* __restrict__ emb, const float* __restrict__ h,
    const int* __restrict__ idx, const float* __restrict__ w,
    const float* __restrict__ Wo1, const float* __restrict__ Wo2,
    const float* __restrict__ bo2, float* __restrict__ out)
{
    __shared__ float w1[32 * 32];
    __shared__ float w2[16 * 32];
    __shared__ float b2[32];
    const int tid = threadIdx.x;
    for (int i = tid; i < 1024; i += 256) w1[i] = Wo1[i];
    for (int i = tid; i < 512;  i += 256) w2[i] = Wo2[i];
    if (tid < 32) b2[tid] = bo2[tid];
    __syncthreads();

    const int row = blockIdx.x * 256 + tid;

    float e[32];
    #pragma unroll
    for (int i = 0; i < 8; i++)
        *(float4*)&e[i * 4] = *(const float4*)(emb + (size_t)row * 32 + i * 4);

    float msum[8], mmax[8];
    #pragma unroll
    for (int d = 0; d < 8; d++) { msum[d] = 0.f; mmax[d] = -FLT_MAX; }

    #pragma unroll
    for (int k = 0; k < 4; k++) {
        const int g   = idx[(size_t)row * 4 + k];
        const float wk = w[(size_t)row * 4 + k];
        float hv[8];
        *(float4*)&hv[0] = *(const float4*)(h + (size_t)g * 8);
        *(float4*)&hv[4] = *(const float4*)(h + (size_t)g * 8 + 4);
        #pragma unroll
        for (int d = 0; d < 8; d++) {
            const float m = hv[d] * wk;
            msum[d] += m;
            mmax[d] = fmaxf(mmax[d], m);
        }
    }

    float agg[16];
    #pragma unroll
    for (int d = 0; d < 8; d++) { agg[d] = msum[d] * 0.25f; agg[8 + d] = mmax[d]; }

    #pragma unroll
    for (int j = 0; j < 32; j++) {
        float a = e[0] * w1[j];
        #pragma unroll
        for (int k = 1; k < 32; k++) a = fmaf(e[k], w1[k * 32 + j], a);
        float g = agg[0] * w2[j];
        #pragma unroll
        for (int k = 1; k < 16; k++) g = fmaf(agg[k], w2[k * 32 + j], g);
        out[(size_t)row * 32 + j] = a + g + b2[j];
    }
}

// ======================= concat helpers =======================
__global__ __launch_bounds__(256) void cat2_kernel(
    const float* __restrict__ x, const float* __restrict__ emb, float* __restrict__ out)
{
    const int row = blockIdx.x * 256 + threadIdx.x;
    const float* xr = x + (size_t)row * 12;
    const float* er = emb + (size_t)row * 32;
    float* o = out + (size_t)row * 44;
    #pragma unroll
    for (int i = 0; i < 3; i++) ((float4*)o)[i] = ((const float4*)xr)[i];
    #pragma unroll
    for (int i = 0; i < 8; i++) ((float4*)(o + 12))[i] = ((const float4*)er)[i];
}

__global__ __launch_bounds__(256) void cat3_kernel(
    const float* __restrict__ x, const float* __restrict__ pid, float* __restrict__ out)
{
    const int row = blockIdx.x * 256 + threadIdx.x;
    const float* xr = x + (size_t)row * 12;
    const float* pr = pid + (size_t)row * 12;   // preds_id lives in d_out with ldc=12
    float* o = out + (size_t)row * 18;
    #pragma unroll
    for (int i = 0; i < 12; i++) o[i] = xr[i];
    #pragma unroll
    for (int i = 0; i < 6; i++) o[12 + i] = pr[i];
}

// ======================= host launcher =======================
extern "C" void kernel_launch(void* const* d_in, const int* in_sizes, int n_in,
                              void* d_out, int out_size, void* d_ws, size_t ws_size,
                              hipStream_t stream)
{
    const float* x = (const float*)d_in[0];
    const float* nn1_w[4] = {(const float*)d_in[1], (const float*)d_in[3], (const float*)d_in[5], (const float*)d_in[7]};
    const float* nn1_b[4] = {(const float*)d_in[2], (const float*)d_in[4], (const float*)d_in[6], (const float*)d_in[8]};
    const float* nn2_w[4] = {(const float*)d_in[9],  (const float*)d_in[11], (const float*)d_in[13], (const float*)d_in[15]};
    const float* nn2_b[4] = {(const float*)d_in[10], (const float*)d_in[12], (const float*)d_in[14], (const float*)d_in[16]};
    const float* nn3_w[4] = {(const float*)d_in[17], (const float*)d_in[19], (const float*)d_in[21], (const float*)d_in[23]};
    const float* nn3_b[4] = {(const float*)d_in[18], (const float*)d_in[20], (const float*)d_in[22], (const float*)d_in[24]};
    const float* conv_ws  = (const float*)d_in[25];  // [3,32,4]
    const float* conv_bs  = (const float*)d_in[26];  // [3,4]
    const float* conv_wh  = (const float*)d_in[27];  // [3,32,8]
    const float* conv_bh  = (const float*)d_in[28];  // [3,8]
    const float* conv_wo1 = (const float*)d_in[29];  // [3,32,32]
    const float* conv_wo2 = (const float*)d_in[30];  // [3,16,32]
    const float* conv_bo2 = (const float*)d_in[31];  // [3,32]

    float* outp = (float*)d_out;

    // workspace partition
    char* p = (char*)d_ws;
    auto take = [&](size_t bytes) { char* r = p; p += (bytes + 255) & ~size_t(255); return r; };
    float* bufA = (float*)take((size_t)NN_TOTAL * 256 * 4);
    float* bufB = (float*)take((size_t)NN_TOTAL * 256 * 4);
    float* embA = (float*)take((size_t)NN_TOTAL * 32 * 4);
    float* embB = (float*)take((size_t)NN_TOTAL * 32 * 4);
    float* sbuf = (float*)take((size_t)NN_TOTAL * 4 * 4);
    float* sqb  = (float*)take((size_t)NN_TOTAL * 4);
    float* hbuf = (float*)take((size_t)NN_TOTAL * 8 * 4);
    int*   idxb = (int*)take((size_t)NN_TOTAL * 4 * 4);
    float* wbuf = (float*)take((size_t)NN_TOTAL * 4 * 4);

    auto gemm = [&](const float* A, const float* W, const float* b, float* C,
                    int N, int K, int lda, int ldc, int act) {
        dim3 g(NN_TOTAL / 128, (N + 127) / 128);
        gemm_bias_act<<<g, 256, 0, stream>>>(A, W, b, C, N, K, lda, ldc, act);
    };

    // ---- nn1 MLP: 12 -> 126 -> 126 -> 126 -> 32
    gemm(x,    nn1_w[0], nn1_b[0], bufA, 126, 12,  12,  126, 1);
    gemm(bufA, nn1_w[1], nn1_b[1], bufB, 126, 126, 126, 126, 1);
    gemm(bufB, nn1_w[2], nn1_b[2], bufA, 126, 126, 126, 126, 1);
    gemm(bufA, nn1_w[3], nn1_b[3], embA, 32,  126, 126, 32,  0);

    // ---- 3 GravNet convs
    float* ecur = embA;
    float* enext = embB;
    for (int i = 0; i < 3; i++) {
        conv_proj<<<NN_TOTAL / 256, 256, 0, stream>>>(
            ecur, conv_ws + i * 128, conv_bs + i * 4, conv_wh + i * 256, conv_bh + i * 8,
            sbuf, sqb, hbuf);
        knn_top4_v2<<<NN_TOTAL / 64, 256, 0, stream>>>(sbuf, sqb, idxb, wbuf);
        conv_agg<<<NN_TOTAL / 256, 256, 0, stream>>>(
            ecur, hbuf, idxb, wbuf,
            conv_wo1 + i * 1024, conv_wo2 + i * 512, conv_bo2 + i * 32, enext);
        float* t = ecur; ecur = enext; enext = t;
    }
    // ecur == final emb

    // ---- nn2 MLP: concat(x, emb)=44 -> 256 -> 256 -> 256 -> 6  (writes d_out cols 0..5)
    cat2_kernel<<<NN_TOTAL / 256, 256, 0, stream>>>(x, ecur, bufA);
    gemm(bufA, nn2_w[0], nn2_b[0], bufB, 256, 44,  44,  256, 1);
    gemm(bufB, nn2_w[1], nn2_b[1], bufA, 256, 256, 256, 256, 1);
    gemm(bufA, nn2_w[2], nn2_b[2], bufB, 256, 256, 256, 256, 1);
    gemm(bufB, nn2_w[3], nn2_b[3], outp, 6,   256, 256, 12,  0);

    // ---- nn3 MLP: concat(x, preds_id)=18 -> 256 -> 256 -> 256 -> 6 (writes d_out cols 6..11)
    cat3_kernel<<<NN_TOTAL / 256, 256, 0, stream>>>(x, outp, bufA);
    gemm(bufA, nn3_w[0], nn3_b[0], bufB, 256, 18,  18,  256, 1);
    gemm(bufB, nn3_w[1], nn3_b[1], bufA, 256, 256, 256, 256, 1);
    gemm(bufA, nn3_w[2], nn3_b[2], bufB, 256, 256, 256, 256, 1);
    gemm(bufB, nn3_w[3], nn3_b[3], outp + 6, 6, 256, 256, 12, 0);
}

// Round 3
// 1128.242 us; speedup vs baseline: 1.7519x; 1.0629x over previous
//
#include <hip/hip_runtime.h>
#include <hip/hip_bf16.h>
#include <cfloat>
#include <climits>

#define NN_TOTAL 32768   // 8 * 4096 rows
#define NPTS     4096

// ======================= tiled fp32 GEMM + bias + optional ELU =======================
// C[M][N] = A[M][K] @ W[K][N] + bias ; act=1 -> ELU
// BM=BN=128, BK=8, 256 threads, 8x8 microtile per thread. M must be multiple of 128.
__global__ __launch_bounds__(256) void gemm_bias_act(
    const float* __restrict__ A, const float* __restrict__ W,
    const float* __restrict__ bias, float* __restrict__ C,
    int N, int K, int lda, int ldc, int act)
{
    __shared__ float As[8][128];
    __shared__ float Bs[8][128];
    const int tid  = threadIdx.x;
    const int row0 = blockIdx.x * 128;
    const int col0 = blockIdx.y * 128;
    const int tx = tid & 15;        // 16 col-groups
    const int ty = tid >> 4;        // 16 row-groups
    const int crow = ty * 8;
    const int ccol = tx * 8;

    float acc[8][8];
    #pragma unroll
    for (int i = 0; i < 8; i++)
        #pragma unroll
        for (int j = 0; j < 8; j++) acc[i][j] = 0.f;

    for (int k0 = 0; k0 < K; k0 += 8) {
        // ---- stage A tile: 128 rows x 8 k, thread t -> row t/2, k-quad t%2
        {
            const int m  = tid >> 1;
            const int kq = (tid & 1) * 4;
            const int gm = row0 + m;
            const float* ap = A + (size_t)gm * lda + k0 + kq;
            float t0, t1, t2, t3;
            t0 = (k0 + kq + 0 < K) ? ap[0] : 0.f;
            t1 = (k0 + kq + 1 < K) ? ap[1] : 0.f;
            t2 = (k0 + kq + 2 < K) ? ap[2] : 0.f;
            t3 = (k0 + kq + 3 < K) ? ap[3] : 0.f;
            As[kq + 0][m] = t0;
            As[kq + 1][m] = t1;
            As[kq + 2][m] = t2;
            As[kq + 3][m] = t3;
        }
        // ---- stage B tile: 8 k x 128 n, thread t -> k t/32, n-quad t%32
        {
            const int kk = tid >> 5;
            const int n  = (tid & 31) * 4;
            const int gk = k0 + kk;
            const int gn = col0 + n;
            float4 v = make_float4(0.f, 0.f, 0.f, 0.f);
            if (gk < K) {
                const float* bp = W + (size_t)gk * N + gn;
                v.x = (gn + 0 < N) ? bp[0] : 0.f;
                v.y = (gn + 1 < N) ? bp[1] : 0.f;
                v.z = (gn + 2 < N) ? bp[2] : 0.f;
                v.w = (gn + 3 < N) ? bp[3] : 0.f;
            }
            *(float4*)&Bs[kk][n] = v;
        }
        __syncthreads();

        #pragma unroll
        for (int k = 0; k < 8; k++) {
            float a[8], b[8];
            *(float4*)&a[0] = *(float4*)&As[k][crow];
            *(float4*)&a[4] = *(float4*)&As[k][crow + 4];
            *(float4*)&b[0] = *(float4*)&Bs[k][ccol];
            *(float4*)&b[4] = *(float4*)&Bs[k][ccol + 4];
            #pragma unroll
            for (int i = 0; i < 8; i++)
                #pragma unroll
                for (int j = 0; j < 8; j++)
                    acc[i][j] = fmaf(a[i], b[j], acc[i][j]);
        }
        __syncthreads();
    }

    // ---- epilogue
    #pragma unroll
    for (int i = 0; i < 8; i++) {
        const int gr = row0 + crow + i;
        #pragma unroll
        for (int j = 0; j < 8; j++) {
            const int gc = col0 + ccol + j;
            if (gc < N) {
                float v = acc[i][j] + bias[gc];
                if (act) v = (v > 0.f) ? v : expm1f(v);
                C[(size_t)gr * ldc + gc] = v;
            }
        }
    }
}

// ======================= GravNet: projections s,h and |s|^2 =======================
__global__ __launch_bounds__(256) void conv_proj(
    const float* __restrict__ emb, const float* __restrict__ Ws,
    const float* __restrict__ bs, const float* __restrict__ Wh,
    const float* __restrict__ bh,
    float* __restrict__ s_out, float* __restrict__ sq_out, float* __restrict__ h_out)
{
    __shared__ float ws_s[32 * 4];
    __shared__ float wh_s[32 * 8];
    __shared__ float bs_s[4];
    __shared__ float bh_s[8];
    const int tid = threadIdx.x;
    if (tid < 128) ws_s[tid] = Ws[tid];
    if (tid >= 128 && tid < 128 + 4) bs_s[tid - 128] = bs[tid - 128];
    if (tid >= 136 && tid < 136 + 8) bh_s[tid - 136] = bh[tid - 136];
    for (int i = tid; i < 256; i += 256) wh_s[i] = Wh[i];
    __syncthreads();

    const int row = blockIdx.x * 256 + tid;
    float e[32];
    #pragma unroll
    for (int i = 0; i < 8; i++)
        *(float4*)&e[i * 4] = *(const float4*)(emb + (size_t)row * 32 + i * 4);

    float sv[4];
    #pragma unroll
    for (int c = 0; c < 4; c++) {
        float a = e[0] * ws_s[c];
        #pragma unroll
        for (int k = 1; k < 32; k++) a = fmaf(e[k], ws_s[k * 4 + c], a);
        sv[c] = a + bs_s[c];
    }
    float sq = sv[0] * sv[0];
    sq = fmaf(sv[1], sv[1], sq);
    sq = fmaf(sv[2], sv[2], sq);
    sq = fmaf(sv[3], sv[3], sq);

    float hv[8];
    #pragma unroll
    for (int c = 0; c < 8; c++) {
        float a = e[0] * wh_s[c];
        #pragma unroll
        for (int k = 1; k < 32; k++) a = fmaf(e[k], wh_s[k * 8 + c], a);
        hv[c] = a + bh_s[c];
    }

    *(float4*)(s_out + (size_t)row * 4) = *(float4*)&sv[0];
    sq_out[row] = sq;
    *(float4*)(h_out + (size_t)row * 8)     = *(float4*)&hv[0];
    *(float4*)(h_out + (size_t)row * 8 + 4) = *(float4*)&hv[4];
}

// ======================= kNN top-4 v3: candidate-split partials + merge =======================
// Block = 64 points x 1024 candidates (1/4 of batch). Grid = (NN/64)*4 = 2048 blocks
// -> 8 blocks/CU, 32 waves/CU. Each of 4 waves covers 256 candidates for all 64
// points (lane = point, LDS broadcast reads). Sorted (d2,idx) top-4 per wave in
// registers; wave 0 merges the block's 4 lists and writes a sorted partial to
// workspace. knn_merge then merges the 4 block-partials per point.
__device__ __forceinline__ void merge44(const float* ad, const int* ai,
                                        const float* bd, const int* bi,
                                        float* od, int* oi)
{
    int a = 0, b = 0;
    #pragma unroll
    for (int k = 0; k < 4; ++k) {
        bool ta;
        if (a < 4 && b < 4)
            ta = (ad[a] < bd[b]) || (ad[a] == bd[b] && ai[a] < bi[b]);
        else
            ta = (a < 4);
        if (ta) { od[k] = ad[a]; oi[k] = ai[a]; ++a; }
        else    { od[k] = bd[b]; oi[k] = bi[b]; ++b; }
    }
}

#define CTILE 512

__global__ __launch_bounds__(256) void knn_top4_part(
    const float* __restrict__ s, const float* __restrict__ sq,
    float* __restrict__ pd, int* __restrict__ pi)
{
    __shared__ float4 cs[CTILE];
    __shared__ float  csq[CTILE];
    __shared__ float  md[4][64][4];
    __shared__ int    mi[4][64][4];

    const int tid  = threadIdx.x;
    const int wv   = tid >> 6;
    const int ln   = tid & 63;
    const int pg   = blockIdx.x >> 2;          // point group (64 points)
    const int sp   = blockIdx.x & 3;           // candidate split (1024 cands)
    const int p0   = pg * 64;
    const int base = (p0 >> 12) << 12;         // batch base row
    const int row  = p0 + ln;

    const float4 sn  = *(const float4*)(s + (size_t)row * 4);
    const float  sqn = sq[row];

    float bd[4] = {FLT_MAX, FLT_MAX, FLT_MAX, FLT_MAX};
    int   bi[4] = {INT_MAX, INT_MAX, INT_MAX, INT_MAX};

    const int m0s = sp * 1024;
    for (int t = 0; t < 2; ++t) {
        const int m0 = m0s + t * CTILE;
        __syncthreads();
        #pragma unroll
        for (int j = tid; j < CTILE; j += 256) {
            const int gm = base + m0 + j;
            cs[j]  = *(const float4*)(s + (size_t)gm * 4);
            csq[j] = sq[gm];
        }
        __syncthreads();

        const int c0 = wv * 128;               // this wave's slice of the tile
        #pragma unroll 4
        for (int i = 0; i < 128; ++i) {
            const float4 cm = cs[c0 + i];
            const float  cq = csq[c0 + i];
            float dot = sn.x * cm.x;
            dot = fmaf(sn.y, cm.y, dot);
            dot = fmaf(sn.z, cm.z, dot);
            dot = fmaf(sn.w, cm.w, dot);
            const float d2 = (sqn + cq) - 2.f * dot;
            const int m = m0 + c0 + i;         // ascending within wave stream
            if (d2 < bd[3]) {                  // strict <: earlier index wins ties
                bd[3] = d2; bi[3] = m;
                if (d2 < bd[2]) {
                    bd[3] = bd[2]; bi[3] = bi[2]; bd[2] = d2; bi[2] = m;
                    if (d2 < bd[1]) {
                        bd[2] = bd[1]; bi[2] = bi[1]; bd[1] = d2; bi[1] = m;
                        if (d2 < bd[0]) {
                            bd[1] = bd[0]; bi[1] = bi[0]; bd[0] = d2; bi[0] = m;
                        }
                    }
                }
            }
        }
    }

    #pragma unroll
    for (int k = 0; k < 4; ++k) { md[wv][ln][k] = bd[k]; mi[wv][ln][k] = bi[k]; }
    __syncthreads();

    if (wv == 0) {
        float l0d[4], l1d[4], l2d[4], l3d[4];
        int   l0i[4], l1i[4], l2i[4], l3i[4];
        #pragma unroll
        for (int k = 0; k < 4; ++k) {
            l0d[k] = md[0][ln][k]; l0i[k] = mi[0][ln][k];
            l1d[k] = md[1][ln][k]; l1i[k] = mi[1][ln][k];
            l2d[k] = md[2][ln][k]; l2i[k] = mi[2][ln][k];
            l3d[k] = md[3][ln][k]; l3i[k] = mi[3][ln][k];
        }
        float m01d[4], m23d[4], fd[4];
        int   m01i[4], m23i[4], fi[4];
        merge44(l0d, l0i, l1d, l1i, m01d, m01i);
        merge44(l2d, l2i, l3d, l3i, m23d, m23i);
        merge44(m01d, m01i, m23d, m23i, fd, fi);

        const size_t o = ((size_t)blockIdx.x * 64 + ln) * 4;   // [(pg*4+sp)][ln][4]
        *(float4*)(pd + o) = *(float4*)&fd[0];
        *(int4*)(pi + o)   = *(int4*)&fi[0];
    }
}

// merge the 4 candidate-split partials per point; emit final idx (global) + weight
__global__ __launch_bounds__(256) void knn_merge(
    const float* __restrict__ pd, const int* __restrict__ pi,
    int* __restrict__ idx_out, float* __restrict__ w_out)
{
    const int row  = blockIdx.x * 256 + threadIdx.x;
    const int pg   = row >> 6;
    const int ln   = row & 63;
    const int base = (row >> 12) << 12;

    float d[4][4];
    int   ii[4][4];
    #pragma unroll
    for (int sp = 0; sp < 4; ++sp) {
        const size_t o = (((size_t)pg * 4 + sp) * 64 + ln) * 4;
        *(float4*)&d[sp][0] = *(const float4*)(pd + o);
        *(int4*)&ii[sp][0]  = *(const int4*)(pi + o);
    }
    float m01d[4], m23d[4], fd[4];
    int   m01i[4], m23i[4], fi[4];
    merge44(d[0], ii[0], d[1], ii[1], m01d, m01i);
    merge44(d[2], ii[2], d[3], ii[3], m23d, m23i);
    merge44(m01d, m01i, m23d, m23i, fd, fi);

    #pragma unroll
    for (int k = 0; k < 4; ++k) {
        idx_out[(size_t)row * 4 + k] = base + fi[k];
        w_out[(size_t)row * 4 + k]   = expf(-10.f * fmaxf(fd[k], 0.f));
    }
}

// ======================= GravNet: aggregate + output linear =======================
__global__ __launch_bounds__(256) void conv_agg(
    const float* __restrict__ emb, const float* __restrict__ h,
    const int* __restrict__ idx, const float* __restrict__ w,
    const float* __restrict__ Wo1, const float* __restrict__ Wo2,
    const float* __restrict__ bo2, float* __restrict__ out)
{
    __shared__ float w1[32 * 32];
    __shared__ float w2[16 * 32];
    __shared__ float b2[32];
    const int tid = threadIdx.x;
    for (int i = tid; i < 1024; i += 256) w1[i] = Wo1[i];
    for (int i = tid; i < 512;  i += 256) w2[i] = Wo2[i];
    if (tid < 32) b2[tid] = bo2[tid];
    __syncthreads();

    const int row = blockIdx.x * 256 + tid;

    float e[32];
    #pragma unroll
    for (int i = 0; i < 8; i++)
        *(float4*)&e[i * 4] = *(const float4*)(emb + (size_t)row * 32 + i * 4);

    float msum[8], mmax[8];
    #pragma unroll
    for (int d = 0; d < 8; d++) { msum[d] = 0.f; mmax[d] = -FLT_MAX; }

    #pragma unroll
    for (int k = 0; k < 4; k++) {
        const int g   = idx[(size_t)row * 4 + k];
        const float wk = w[(size_t)row * 4 + k];
        float hv[8];
        *(float4*)&hv[0] = *(const float4*)(h + (size_t)g * 8);
        *(float4*)&hv[4] = *(const float4*)(h + (size_t)g * 8 + 4);
        #pragma unroll
        for (int d = 0; d < 8; d++) {
            const float m = hv[d] * wk;
            msum[d] += m;
            mmax[d] = fmaxf(mmax[d], m);
        }
    }

    float agg[16];
    #pragma unroll
    for (int d = 0; d < 8; d++) { agg[d] = msum[d] * 0.25f; agg[8 + d] = mmax[d]; }

    #pragma unroll
    for (int j = 0; j < 32; j++) {
        float a = e[0] * w1[j];
        #pragma unroll
        for (int k = 1; k < 32; k++) a = fmaf(e[k], w1[k * 32 + j], a);
        float g = agg[0] * w2[j];
        #pragma unroll
        for (int k = 1; k < 16; k++) g = fmaf(agg[k], w2[k * 32 + j], g);
        out[(size_t)row * 32 + j] = a + g + b2[j];
    }
}

// ======================= concat helpers =======================
__global__ __launch_bounds__(256) void cat2_kernel(
    const float* __restrict__ x, const float* __restrict__ emb, float* __restrict__ out)
{
    const int row = blockIdx.x * 256 + threadIdx.x;
    const float* xr = x + (size_t)row * 12;
    const float* er = emb + (size_t)row * 32;
    float* o = out + (size_t)row * 44;
    #pragma unroll
    for (int i = 0; i < 3; i++) ((float4*)o)[i] = ((const float4*)xr)[i];
    #pragma unroll
    for (int i = 0; i < 8; i++) ((float4*)(o + 12))[i] = ((const float4*)er)[i];
}

__global__ __launch_bounds__(256) void cat3_kernel(
    const float* __restrict__ x, const float* __restrict__ pid, float* __restrict__ out)
{
    const int row = blockIdx.x * 256 + threadIdx.x;
    const float* xr = x + (size_t)row * 12;
    const float* pr = pid + (size_t)row * 12;   // preds_id lives in d_out with ldc=12
    float* o = out + (size_t)row * 18;
    #pragma unroll
    for (int i = 0; i < 12; i++) o[i] = xr[i];
    #pragma unroll
    for (int i = 0; i < 6; i++) o[12 + i] = pr[i];
}

// ======================= host launcher =======================
extern "C" void kernel_launch(void* const* d_in, const int* in_sizes, int n_in,
                              void* d_out, int out_size, void* d_ws, size_t ws_size,
                              hipStream_t stream)
{
    const float* x = (const float*)d_in[0];
    const float* nn1_w[4] = {(const float*)d_in[1], (const float*)d_in[3], (const float*)d_in[5], (const float*)d_in[7]};
    const float* nn1_b[4] = {(const float*)d_in[2], (const float*)d_in[4], (const float*)d_in[6], (const float*)d_in[8]};
    const float* nn2_w[4] = {(const float*)d_in[9],  (const float*)d_in[11], (const float*)d_in[13], (const float*)d_in[15]};
    const float* nn2_b[4] = {(const float*)d_in[10], (const float*)d_in[12], (const float*)d_in[14], (const float*)d_in[16]};
    const float* nn3_w[4] = {(const float*)d_in[17], (const float*)d_in[19], (const float*)d_in[21], (const float*)d_in[23]};
    const float* nn3_b[4] = {(const float*)d_in[18], (const float*)d_in[20], (const float*)d_in[22], (const float*)d_in[24]};
    const float* conv_ws  = (const float*)d_in[25];  // [3,32,4]
    const float* conv_bs  = (const float*)d_in[26];  // [3,4]
    const float* conv_wh  = (const float*)d_in[27];  // [3,32,8]
    const float* conv_bh  = (const float*)d_in[28];  // [3,8]
    const float* conv_wo1 = (const float*)d_in[29];  // [3,32,32]
    const float* conv_wo2 = (const float*)d_in[30];  // [3,16,32]
    const float* conv_bo2 = (const float*)d_in[31];  // [3,32]

    float* outp = (float*)d_out;

    // workspace partition
    char* p = (char*)d_ws;
    auto take = [&](size_t bytes) { char* r = p; p += (bytes + 255) & ~size_t(255); return r; };
    float* bufA = (float*)take((size_t)NN_TOTAL * 256 * 4);
    float* bufB = (float*)take((size_t)NN_TOTAL * 256 * 4);
    float* embA = (float*)take((size_t)NN_TOTAL * 32 * 4);
    float* embB = (float*)take((size_t)NN_TOTAL * 32 * 4);
    float* sbuf = (float*)take((size_t)NN_TOTAL * 4 * 4);
    float* sqb  = (float*)take((size_t)NN_TOTAL * 4);
    float* hbuf = (float*)take((size_t)NN_TOTAL * 8 * 4);
    int*   idxb = (int*)take((size_t)NN_TOTAL * 4 * 4);
    float* wbuf = (float*)take((size_t)NN_TOTAL * 4 * 4);
    float* pdb  = (float*)take((size_t)NN_TOTAL * 4 * 4 * 4);   // per-split partials (d2)
    int*   pib  = (int*)take((size_t)NN_TOTAL * 4 * 4 * 4);     // per-split partials (idx)

    auto gemm = [&](const float* A, const float* W, const float* b, float* C,
                    int N, int K, int lda, int ldc, int act) {
        dim3 g(NN_TOTAL / 128, (N + 127) / 128);
        gemm_bias_act<<<g, 256, 0, stream>>>(A, W, b, C, N, K, lda, ldc, act);
    };

    // ---- nn1 MLP: 12 -> 126 -> 126 -> 126 -> 32
    gemm(x,    nn1_w[0], nn1_b[0], bufA, 126, 12,  12,  126, 1);
    gemm(bufA, nn1_w[1], nn1_b[1], bufB, 126, 126, 126, 126, 1);
    gemm(bufB, nn1_w[2], nn1_b[2], bufA, 126, 126, 126, 126, 1);
    gemm(bufA, nn1_w[3], nn1_b[3], embA, 32,  126, 126, 32,  0);

    // ---- 3 GravNet convs
    float* ecur = embA;
    float* enext = embB;
    for (int i = 0; i < 3; i++) {
        conv_proj<<<NN_TOTAL / 256, 256, 0, stream>>>(
            ecur, conv_ws + i * 128, conv_bs + i * 4, conv_wh + i * 256, conv_bh + i * 8,
            sbuf, sqb, hbuf);
        knn_top4_part<<<(NN_TOTAL / 64) * 4, 256, 0, stream>>>(sbuf, sqb, pdb, pib);
        knn_merge<<<NN_TOTAL / 256, 256, 0, stream>>>(pdb, pib, idxb, wbuf);
        conv_agg<<<NN_TOTAL / 256, 256, 0, stream>>>(
            ecur, hbuf, idxb, wbuf,
            conv_wo1 + i * 1024, conv_wo2 + i * 512, conv_bo2 + i * 32, enext);
        float* t = ecur; ecur = enext; enext = t;
    }
    // ecur == final emb

    // ---- nn2 MLP: concat(x, emb)=44 -> 256 -> 256 -> 256 -> 6  (writes d_out cols 0..5)
    cat2_kernel<<<NN_TOTAL / 256, 256, 0, stream>>>(x, ecur, bufA);
    gemm(bufA, nn2_w[0], nn2_b[0], bufB, 256, 44,  44,  256, 1);
    gemm(bufB, nn2_w[1], nn2_b[1], bufA, 256, 256, 256, 256, 1);
    gemm(bufA, nn2_w[2], nn2_b[2], bufB, 256, 256, 256, 256, 1);
    gemm(bufB, nn2_w[3], nn2_b[3], outp, 6,   256, 256, 12,  0);

    // ---- nn3 MLP: concat(x, preds_id)=18 -> 256 -> 256 -> 256 -> 6 (writes d_out cols 6..11)
    cat3_kernel<<<NN_TOTAL / 256, 256, 0, stream>>>(x, outp, bufA);
    gemm(bufA, nn3_w[0], nn3_b[0], bufB, 256, 18,  18,  256, 1);
    gemm(bufB, nn3_w[1], nn3_b[1], bufA, 256, 256, 256, 256, 1);
    gemm(bufA, nn3_w[2], nn3_b[2], bufB, 256, 256, 256, 256, 1);
    gemm(bufB, nn3_w[3], nn3_b[3], outp + 6, 6, 256, 256, 12, 0);
}

// Round 4
// 688.392 us; speedup vs baseline: 2.8713x; 1.6390x over previous
//
#include <hip/hip_runtime.h>
#include <hip/hip_bf16.h>
#include <cfloat>
#include <climits>

#define NN_TOTAL 32768   // 8 * 4096 rows
#define NPTS     4096

typedef __attribute__((ext_vector_type(8))) short short8;
typedef __attribute__((ext_vector_type(4))) float f32x4;

__device__ __forceinline__ void split_bf16(float v, unsigned short& h, unsigned short& l)
{
    __hip_bfloat16 hb = __float2bfloat16(v);
    float hf = __bfloat162float(hb);
    __hip_bfloat16 lb = __float2bfloat16(v - hf);
    h = __builtin_bit_cast(unsigned short, hb);
    l = __builtin_bit_cast(unsigned short, lb);
}

// ======================= weight prep: fp32 [K][N] -> bf16 hi/lo transposed [Np][Kp] =======================
__global__ __launch_bounds__(256) void prep_weight(
    const float* __restrict__ W, unsigned short* __restrict__ th,
    unsigned short* __restrict__ tl, int K, int N, int Kp, int Np)
{
    const int i = blockIdx.x * 256 + threadIdx.x;
    if (i >= Np * Kp) return;
    const int n = i / Kp, k = i - n * Kp;
    const float v = (n < N && k < K) ? W[(size_t)k * N + n] : 0.f;
    unsigned short h, l;
    split_bf16(v, h, l);
    th[i] = h; tl[i] = l;
}

// ======================= activation packers (fp32 -> zero-padded bf16 hi/lo) =======================
__global__ __launch_bounds__(256) void pack_x32(   // x[M][12] -> [M][32]
    const float* __restrict__ x, unsigned short* __restrict__ Xh, unsigned short* __restrict__ Xl)
{
    const int gid = blockIdx.x * 256 + threadIdx.x;   // M*4 threads
    const int r = gid >> 2, c8 = (gid & 3) * 8;
    unsigned short h[8], l[8];
    #pragma unroll
    for (int j = 0; j < 8; ++j) {
        const int col = c8 + j;
        const float v = (col < 12) ? x[(size_t)r * 12 + col] : 0.f;
        split_bf16(v, h[j], l[j]);
    }
    *(int4*)(Xh + (size_t)r * 32 + c8) = *(int4*)h;
    *(int4*)(Xl + (size_t)r * 32 + c8) = *(int4*)l;
}

__global__ __launch_bounds__(256) void cat2_pack(  // [x(12) | emb(32)] -> [M][64]
    const float* __restrict__ x, const float* __restrict__ emb,
    unsigned short* __restrict__ Xh, unsigned short* __restrict__ Xl)
{
    const int gid = blockIdx.x * 256 + threadIdx.x;   // M*8 threads
    const int r = gid >> 3, c8 = (gid & 7) * 8;
    unsigned short h[8], l[8];
    #pragma unroll
    for (int j = 0; j < 8; ++j) {
        const int col = c8 + j;
        float v = 0.f;
        if (col < 12)      v = x[(size_t)r * 12 + col];
        else if (col < 44) v = emb[(size_t)r * 32 + (col - 12)];
        split_bf16(v, h[j], l[j]);
    }
    *(int4*)(Xh + (size_t)r * 64 + c8) = *(int4*)h;
    *(int4*)(Xl + (size_t)r * 64 + c8) = *(int4*)l;
}

__global__ __launch_bounds__(256) void cat3_pack(  // [x(12) | preds_id(6 from d_out ldc12)] -> [M][32]
    const float* __restrict__ x, const float* __restrict__ dout,
    unsigned short* __restrict__ Xh, unsigned short* __restrict__ Xl)
{
    const int gid = blockIdx.x * 256 + threadIdx.x;   // M*4 threads
    const int r = gid >> 2, c8 = (gid & 3) * 8;
    unsigned short h[8], l[8];
    #pragma unroll
    for (int j = 0; j < 8; ++j) {
        const int col = c8 + j;
        float v = 0.f;
        if (col < 12)      v = x[(size_t)r * 12 + col];
        else if (col < 18) v = dout[(size_t)r * 12 + (col - 12)];
        split_bf16(v, h[j], l[j]);
    }
    *(int4*)(Xh + (size_t)r * 32 + c8) = *(int4*)h;
    *(int4*)(Xl + (size_t)r * 32 + c8) = *(int4*)l;
}

// ======================= MFMA bf16x3 GEMM (fp32-accurate) =======================
// C = A @ W + bias, A = Ah+Al [M][Kp] bf16 pair, W as Bt = Bh+Bl [Np][Kp] bf16 pair
// (transposed). BM=BN=128, BK=32, 4 waves (2x2) of 64x64, mfma_f32_16x16x32_bf16.
// acc += Ah*Bh + Ah*Bl + Al*Bh  (Al*Bl ~2^-16, dropped).
// Output: fp32 (Cf,ldcf) or bf16 hi/lo pair (Ch,Cl,ldcb) with zero-pad cols [N,padN).
#define LRS 40   // padded LDS row stride (bf16 elems) for a 32-wide k-tile row
__global__ __launch_bounds__(256, 2) void gemm_mfma3(
    const unsigned short* __restrict__ Ah, const unsigned short* __restrict__ Al,
    const unsigned short* __restrict__ Bh, const unsigned short* __restrict__ Bl,
    const float* __restrict__ bias, int Kp, int N, int act,
    float* __restrict__ Cf, int ldcf,
    unsigned short* __restrict__ Ch, unsigned short* __restrict__ Cl, int ldcb, int padN)
{
    __shared__ unsigned short lds[4][128 * LRS];

    const int tid  = threadIdx.x;
    const int wave = tid >> 6, lane = tid & 63;
    const int wr = wave >> 1, wc = wave & 1;
    const int row0 = blockIdx.x * 128;
    const int col0 = blockIdx.y * 128;
    const int r16 = lane & 15, kg = lane >> 4;

    f32x4 acc[4][4];
    #pragma unroll
    for (int m = 0; m < 4; ++m)
        #pragma unroll
        for (int n = 0; n < 4; ++n)
            #pragma unroll
            for (int r = 0; r < 4; ++r) acc[m][n][r] = 0.f;

    for (int k0 = 0; k0 < Kp; k0 += 32) {
        __syncthreads();
        // stage 4 tiles of [128][32] bf16 (A hi/lo by block-row, Bt hi/lo by block-col)
        #pragma unroll
        for (int c = tid; c < 512; c += 256) {
            const int row = c >> 2, kc = (c & 3) * 8;
            const size_t aoff = (size_t)(row0 + row) * Kp + k0 + kc;
            const size_t boff = (size_t)(col0 + row) * Kp + k0 + kc;
            const int dst = row * LRS + kc;
            *(int4*)&lds[0][dst] = *(const int4*)(Ah + aoff);
            *(int4*)&lds[1][dst] = *(const int4*)(Al + aoff);
            *(int4*)&lds[2][dst] = *(const int4*)(Bh + boff);
            *(int4*)&lds[3][dst] = *(const int4*)(Bl + boff);
        }
        __syncthreads();

        short8 ah[4], al[4], bh[4], bl[4];
        #pragma unroll
        for (int m = 0; m < 4; ++m) {
            const int ar = (wr * 64 + m * 16 + r16) * LRS + kg * 8;
            ah[m] = *(const short8*)&lds[0][ar];
            al[m] = *(const short8*)&lds[1][ar];
            const int br = (wc * 64 + m * 16 + r16) * LRS + kg * 8;
            bh[m] = *(const short8*)&lds[2][br];
            bl[m] = *(const short8*)&lds[3][br];
        }
        #pragma unroll
        for (int m = 0; m < 4; ++m)
            #pragma unroll
            for (int n = 0; n < 4; ++n) {
                acc[m][n] = __builtin_amdgcn_mfma_f32_16x16x32_bf16(ah[m], bh[n], acc[m][n], 0, 0, 0);
                acc[m][n] = __builtin_amdgcn_mfma_f32_16x16x32_bf16(ah[m], bl[n], acc[m][n], 0, 0, 0);
                acc[m][n] = __builtin_amdgcn_mfma_f32_16x16x32_bf16(al[m], bh[n], acc[m][n], 0, 0, 0);
            }
    }

    // epilogue: C/D layout col=lane&15, row=(lane>>4)*4+reg (verified m89/m91)
    #pragma unroll
    for (int m = 0; m < 4; ++m) {
        #pragma unroll
        for (int n = 0; n < 4; ++n) {
            const int col = col0 + wc * 64 + n * 16 + r16;
            #pragma unroll
            for (int r = 0; r < 4; ++r) {
                const int row = row0 + wr * 64 + m * 16 + kg * 4 + r;
                if (col < N) {
                    float v = acc[m][n][r] + bias[col];
                    if (act) v = (v > 0.f) ? v : expm1f(v);
                    if (Cf) {
                        Cf[(size_t)row * ldcf + col] = v;
                    } else {
                        unsigned short h, l;
                        split_bf16(v, h, l);
                        Ch[(size_t)row * ldcb + col] = h;
                        Cl[(size_t)row * ldcb + col] = l;
                    }
                } else if (Ch && col < padN) {
                    Ch[(size_t)row * ldcb + col] = 0;
                    Cl[(size_t)row * ldcb + col] = 0;
                }
            }
        }
    }
}

// ======================= GravNet: projections s,h and |s|^2 =======================
__global__ __launch_bounds__(256) void conv_proj(
    const float* __restrict__ emb, const float* __restrict__ Ws,
    const float* __restrict__ bs, const float* __restrict__ Wh,
    const float* __restrict__ bh,
    float* __restrict__ s_out, float* __restrict__ sq_out, float* __restrict__ h_out)
{
    __shared__ float ws_s[32 * 4];
    __shared__ float wh_s[32 * 8];
    __shared__ float bs_s[4];
    __shared__ float bh_s[8];
    const int tid = threadIdx.x;
    if (tid < 128) ws_s[tid] = Ws[tid];
    if (tid >= 128 && tid < 128 + 4) bs_s[tid - 128] = bs[tid - 128];
    if (tid >= 136 && tid < 136 + 8) bh_s[tid - 136] = bh[tid - 136];
    for (int i = tid; i < 256; i += 256) wh_s[i] = Wh[i];
    __syncthreads();

    const int row = blockIdx.x * 256 + tid;
    float e[32];
    #pragma unroll
    for (int i = 0; i < 8; i++)
        *(float4*)&e[i * 4] = *(const float4*)(emb + (size_t)row * 32 + i * 4);

    float sv[4];
    #pragma unroll
    for (int c = 0; c < 4; c++) {
        float a = e[0] * ws_s[c];
        #pragma unroll
        for (int k = 1; k < 32; k++) a = fmaf(e[k], ws_s[k * 4 + c], a);
        sv[c] = a + bs_s[c];
    }
    float sq = sv[0] * sv[0];
    sq = fmaf(sv[1], sv[1], sq);
    sq = fmaf(sv[2], sv[2], sq);
    sq = fmaf(sv[3], sv[3], sq);

    float hv[8];
    #pragma unroll
    for (int c = 0; c < 8; c++) {
        float a = e[0] * wh_s[c];
        #pragma unroll
        for (int k = 1; k < 32; k++) a = fmaf(e[k], wh_s[k * 8 + c], a);
        hv[c] = a + bh_s[c];
    }

    *(float4*)(s_out + (size_t)row * 4) = *(float4*)&sv[0];
    sq_out[row] = sq;
    *(float4*)(h_out + (size_t)row * 8)     = *(float4*)&hv[0];
    *(float4*)(h_out + (size_t)row * 8 + 4) = *(float4*)&hv[4];
}

// ======================= kNN top-4: candidate-split partials + merge =======================
__device__ __forceinline__ void merge44(const float* ad, const int* ai,
                                        const float* bd, const int* bi,
                                        float* od, int* oi)
{
    int a = 0, b = 0;
    #pragma unroll
    for (int k = 0; k < 4; ++k) {
        bool ta;
        if (a < 4 && b < 4)
            ta = (ad[a] < bd[b]) || (ad[a] == bd[b] && ai[a] < bi[b]);
        else
            ta = (a < 4);
        if (ta) { od[k] = ad[a]; oi[k] = ai[a]; ++a; }
        else    { od[k] = bd[b]; oi[k] = bi[b]; ++b; }
    }
}

#define CTILE 512

__global__ __launch_bounds__(256) void knn_top4_part(
    const float* __restrict__ s, const float* __restrict__ sq,
    float* __restrict__ pd, int* __restrict__ pi)
{
    __shared__ float4 cs[CTILE];
    __shared__ float  csq[CTILE];
    __shared__ float  md[4][64][4];
    __shared__ int    mi[4][64][4];

    const int tid  = threadIdx.x;
    const int wv   = tid >> 6;
    const int ln   = tid & 63;
    const int pg   = blockIdx.x >> 2;          // point group (64 points)
    const int sp   = blockIdx.x & 3;           // candidate split (1024 cands)
    const int p0   = pg * 64;
    const int base = (p0 >> 12) << 12;         // batch base row
    const int row  = p0 + ln;

    const float4 sn  = *(const float4*)(s + (size_t)row * 4);
    const float  sqn = sq[row];

    float bd[4] = {FLT_MAX, FLT_MAX, FLT_MAX, FLT_MAX};
    int   bi[4] = {INT_MAX, INT_MAX, INT_MAX, INT_MAX};

    const int m0s = sp * 1024;
    for (int t = 0; t < 2; ++t) {
        const int m0 = m0s + t * CTILE;
        __syncthreads();
        #pragma unroll
        for (int j = tid; j < CTILE; j += 256) {
            const int gm = base + m0 + j;
            cs[j]  = *(const float4*)(s + (size_t)gm * 4);
            csq[j] = sq[gm];
        }
        __syncthreads();

        const int c0 = wv * 128;
        #pragma unroll 4
        for (int i = 0; i < 128; ++i) {
            const float4 cm = cs[c0 + i];
            const float  cq = csq[c0 + i];
            float dot = sn.x * cm.x;
            dot = fmaf(sn.y, cm.y, dot);
            dot = fmaf(sn.z, cm.z, dot);
            dot = fmaf(sn.w, cm.w, dot);
            const float d2 = (sqn + cq) - 2.f * dot;
            const int m = m0 + c0 + i;
            if (d2 < bd[3]) {                  // strict <: earlier index wins ties
                bd[3] = d2; bi[3] = m;
                if (d2 < bd[2]) {
                    bd[3] = bd[2]; bi[3] = bi[2]; bd[2] = d2; bi[2] = m;
                    if (d2 < bd[1]) {
                        bd[2] = bd[1]; bi[2] = bi[1]; bd[1] = d2; bi[1] = m;
                        if (d2 < bd[0]) {
                            bd[1] = bd[0]; bi[1] = bi[0]; bd[0] = d2; bi[0] = m;
                        }
                    }
                }
            }
        }
    }

    #pragma unroll
    for (int k = 0; k < 4; ++k) { md[wv][ln][k] = bd[k]; mi[wv][ln][k] = bi[k]; }
    __syncthreads();

    if (wv == 0) {
        float l0d[4], l1d[4], l2d[4], l3d[4];
        int   l0i[4], l1i[4], l2i[4], l3i[4];
        #pragma unroll
        for (int k = 0; k < 4; ++k) {
            l0d[k] = md[0][ln][k]; l0i[k] = mi[0][ln][k];
            l1d[k] = md[1][ln][k]; l1i[k] = mi[1][ln][k];
            l2d[k] = md[2][ln][k]; l2i[k] = mi[2][ln][k];
            l3d[k] = md[3][ln][k]; l3i[k] = mi[3][ln][k];
        }
        float m01d[4], m23d[4], fd[4];
        int   m01i[4], m23i[4], fi[4];
        merge44(l0d, l0i, l1d, l1i, m01d, m01i);
        merge44(l2d, l2i, l3d, l3i, m23d, m23i);
        merge44(m01d, m01i, m23d, m23i, fd, fi);

        const size_t o = ((size_t)blockIdx.x * 64 + ln) * 4;
        *(float4*)(pd + o) = *(float4*)&fd[0];
        *(int4*)(pi + o)   = *(int4*)&fi[0];
    }
}

__global__ __launch_bounds__(256) void knn_merge(
    const float* __restrict__ pd, const int* __restrict__ pi,
    int* __restrict__ idx_out, float* __restrict__ w_out)
{
    const int row  = blockIdx.x * 256 + threadIdx.x;
    const int pg   = row >> 6;
    const int ln   = row & 63;
    const int base = (row >> 12) << 12;

    float d[4][4];
    int   ii[4][4];
    #pragma unroll
    for (int sp = 0; sp < 4; ++sp) {
        const size_t o = (((size_t)pg * 4 + sp) * 64 + ln) * 4;
        *(float4*)&d[sp][0] = *(const float4*)(pd + o);
        *(int4*)&ii[sp][0]  = *(const int4*)(pi + o);
    }
    float m01d[4], m23d[4], fd[4];
    int   m01i[4], m23i[4], fi[4];
    merge44(d[0], ii[0], d[1], ii[1], m01d, m01i);
    merge44(d[2], ii[2], d[3], ii[3], m23d, m23i);
    merge44(m01d, m01i, m23d, m23i, fd, fi);

    #pragma unroll
    for (int k = 0; k < 4; ++k) {
        idx_out[(size_t)row * 4 + k] = base + fi[k];
        w_out[(size_t)row * 4 + k]   = expf(-10.f * fmaxf(fd[k], 0.f));
    }
}

// ======================= GravNet: aggregate + output linear =======================
__global__ __launch_bounds__(256) void conv_agg(
    const float* __restrict__ emb, const float* __restrict__ h,
    const int* __restrict__ idx, const float* __restrict__ w,
    const float* __restrict__ Wo1, const float* __restrict__ Wo2,
    const float* __restrict__ bo2, float* __restrict__ out)
{
    __shared__ float w1[32 * 32];
    __shared__ float w2[16 * 32];
    __shared__ float b2[32];
    const int tid = threadIdx.x;
    for (int i = tid; i < 1024; i += 256) w1[i] = Wo1[i];
    for (int i = tid; i < 512;  i += 256) w2[i] = Wo2[i];
    if (tid < 32) b2[tid] = bo2[tid];
    __syncthreads();

    const int row = blockIdx.x * 256 + tid;

    float e[32];
    #pragma unroll
    for (int i = 0; i < 8; i++)
        *(float4*)&e[i * 4] = *(const float4*)(emb + (size_t)row * 32 + i * 4);

    float msum[8], mmax[8];
    #pragma unroll
    for (int d = 0; d < 8; d++) { msum[d] = 0.f; mmax[d] = -FLT_MAX; }

    #pragma unroll
    for (int k = 0; k < 4; k++) {
        const int g   = idx[(size_t)row * 4 + k];
        const float wk = w[(size_t)row * 4 + k];
        float hv[8];
        *(float4*)&hv[0] = *(const float4*)(h + (size_t)g * 8);
        *(float4*)&hv[4] = *(const float4*)(h + (size_t)g * 8 + 4);
        #pragma unroll
        for (int d = 0; d < 8; d++) {
            const float m = hv[d] * wk;
            msum[d] += m;
            mmax[d] = fmaxf(mmax[d], m);
        }
    }

    float agg[16];
    #pragma unroll
    for (int d = 0; d < 8; d++) { agg[d] = msum[d] * 0.25f; agg[8 + d] = mmax[d]; }

    #pragma unroll
    for (int j = 0; j < 32; j++) {
        float a = e[0] * w1[j];
        #pragma unroll
        for (int k = 1; k < 32; k++) a = fmaf(e[k], w1[k * 32 + j], a);
        float g = agg[0] * w2[j];
        #pragma unroll
        for (int k = 1; k < 16; k++) g = fmaf(agg[k], w2[k * 32 + j], g);
        out[(size_t)row * 32 + j] = a + g + b2[j];
    }
}

// ======================= host launcher =======================
extern "C" void kernel_launch(void* const* d_in, const int* in_sizes, int n_in,
                              void* d_out, int out_size, void* d_ws, size_t ws_size,
                              hipStream_t stream)
{
    const float* x = (const float*)d_in[0];
    const float* nn1_w[4] = {(const float*)d_in[1], (const float*)d_in[3], (const float*)d_in[5], (const float*)d_in[7]};
    const float* nn1_b[4] = {(const float*)d_in[2], (const float*)d_in[4], (const float*)d_in[6], (const float*)d_in[8]};
    const float* nn2_w[4] = {(const float*)d_in[9],  (const float*)d_in[11], (const float*)d_in[13], (const float*)d_in[15]};
    const float* nn2_b[4] = {(const float*)d_in[10], (const float*)d_in[12], (const float*)d_in[14], (const float*)d_in[16]};
    const float* nn3_w[4] = {(const float*)d_in[17], (const float*)d_in[19], (const float*)d_in[21], (const float*)d_in[23]};
    const float* nn3_b[4] = {(const float*)d_in[18], (const float*)d_in[20], (const float*)d_in[22], (const float*)d_in[24]};
    const float* conv_ws  = (const float*)d_in[25];  // [3,32,4]
    const float* conv_bs  = (const float*)d_in[26];  // [3,4]
    const float* conv_wh  = (const float*)d_in[27];  // [3,32,8]
    const float* conv_bh  = (const float*)d_in[28];  // [3,8]
    const float* conv_wo1 = (const float*)d_in[29];  // [3,32,32]
    const float* conv_wo2 = (const float*)d_in[30];  // [3,16,32]
    const float* conv_bo2 = (const float*)d_in[31];  // [3,32]

    float* outp = (float*)d_out;
    const int M = NN_TOTAL;

    // ---- workspace partition
    char* p = (char*)d_ws;
    auto take = [&](size_t bytes) { char* r = p; p += (bytes + 255) & ~size_t(255); return r; };
    unsigned short* Xa_h = (unsigned short*)take((size_t)M * 256 * 2);
    unsigned short* Xa_l = (unsigned short*)take((size_t)M * 256 * 2);
    unsigned short* Xb_h = (unsigned short*)take((size_t)M * 256 * 2);
    unsigned short* Xb_l = (unsigned short*)take((size_t)M * 256 * 2);
    float* embA = (float*)take((size_t)M * 32 * 4);
    float* embB = (float*)take((size_t)M * 32 * 4);
    unsigned short* WH = (unsigned short*)take((size_t)400000 * 2);
    unsigned short* WL = (unsigned short*)take((size_t)400000 * 2);

    // conv scratch aliased over Xa (dead during conv loop: nn1 done, cat2 not yet run)
    char* q = (char*)Xa_h;
    auto takeq = [&](size_t bytes) { char* r = q; q += (bytes + 255) & ~size_t(255); return r; };
    float* sbuf = (float*)takeq((size_t)M * 4 * 4);
    float* sqb  = (float*)takeq((size_t)M * 4);
    float* hbuf = (float*)takeq((size_t)M * 8 * 4);
    int*   idxb = (int*)takeq((size_t)M * 4 * 4);
    float* wbuf = (float*)takeq((size_t)M * 4 * 4);
    float* pdb  = (float*)takeq((size_t)M * 4 * 4 * 4);
    int*   pib  = (int*)takeq((size_t)M * 4 * 4 * 4);

    // ---- weight prep: 12 layers, transposed bf16 hi/lo, padded [Np][Kp]
    struct LW { const float* W; int K, N, Kp, Np, off; };
    LW lw[12];
    const float* Ws_[12] = {nn1_w[0], nn1_w[1], nn1_w[2], nn1_w[3],
                            nn2_w[0], nn2_w[1], nn2_w[2], nn2_w[3],
                            nn3_w[0], nn3_w[1], nn3_w[2], nn3_w[3]};
    const int Ks_[12] = {12, 126, 126, 126,  44, 256, 256, 256,  18, 256, 256, 256};
    const int Ns_[12] = {126, 126, 126, 32,  256, 256, 256, 6,   256, 256, 256, 6};
    int off = 0;
    for (int i = 0; i < 12; ++i) {
        lw[i].W = Ws_[i]; lw[i].K = Ks_[i]; lw[i].N = Ns_[i];
        lw[i].Kp = (Ks_[i] + 31) & ~31;
        lw[i].Np = ((Ns_[i] + 127) & ~127);
        lw[i].off = off;
        off += lw[i].Kp * lw[i].Np;
        const int total = lw[i].Kp * lw[i].Np;
        prep_weight<<<(total + 255) / 256, 256, 0, stream>>>(
            lw[i].W, WH + lw[i].off, WL + lw[i].off, lw[i].K, lw[i].N, lw[i].Kp, lw[i].Np);
    }

    auto mfma = [&](const unsigned short* Ah, const unsigned short* Al, int li,
                    const float* bias, int act,
                    float* Cf, int ldcf,
                    unsigned short* Chh, unsigned short* Cll, int ldcb, int padN) {
        dim3 g(M / 128, lw[li].Np / 128);
        gemm_mfma3<<<g, 256, 0, stream>>>(Ah, Al, WH + lw[li].off, WL + lw[li].off,
                                          bias, lw[li].Kp, lw[li].N, act,
                                          Cf, ldcf, Chh, Cll, ldcb, padN);
    };

    // ---- nn1: 12 -> 126 -> 126 -> 126 -> 32(emb, fp32)
    pack_x32<<<M * 4 / 256, 256, 0, stream>>>(x, Xa_h, Xa_l);
    mfma(Xa_h, Xa_l, 0, nn1_b[0], 1, nullptr, 0, Xb_h, Xb_l, 128, 128);
    mfma(Xb_h, Xb_l, 1, nn1_b[1], 1, nullptr, 0, Xa_h, Xa_l, 128, 128);
    mfma(Xa_h, Xa_l, 2, nn1_b[2], 1, nullptr, 0, Xb_h, Xb_l, 128, 128);
    mfma(Xb_h, Xb_l, 3, nn1_b[3], 0, embA, 32, nullptr, nullptr, 0, 0);

    // ---- 3 GravNet convs (fp32, conv scratch aliases Xa which is now dead)
    float* ecur = embA;
    float* enext = embB;
    for (int i = 0; i < 3; i++) {
        conv_proj<<<M / 256, 256, 0, stream>>>(
            ecur, conv_ws + i * 128, conv_bs + i * 4, conv_wh + i * 256, conv_bh + i * 8,
            sbuf, sqb, hbuf);
        knn_top4_part<<<(M / 64) * 4, 256, 0, stream>>>(sbuf, sqb, pdb, pib);
        knn_merge<<<M / 256, 256, 0, stream>>>(pdb, pib, idxb, wbuf);
        conv_agg<<<M / 256, 256, 0, stream>>>(
            ecur, hbuf, idxb, wbuf,
            conv_wo1 + i * 1024, conv_wo2 + i * 512, conv_bo2 + i * 32, enext);
        float* t = ecur; ecur = enext; enext = t;
    }
    // ecur == final emb

    // ---- nn2: cat(x,emb)=44 -> 256 -> 256 -> 256 -> 6 (d_out cols 0..5)
    cat2_pack<<<M * 8 / 256, 256, 0, stream>>>(x, ecur, Xa_h, Xa_l);
    mfma(Xa_h, Xa_l, 4, nn2_b[0], 1, nullptr, 0, Xb_h, Xb_l, 256, 256);
    mfma(Xb_h, Xb_l, 5, nn2_b[1], 1, nullptr, 0, Xa_h, Xa_l, 256, 256);
    mfma(Xa_h, Xa_l, 6, nn2_b[2], 1, nullptr, 0, Xb_h, Xb_l, 256, 256);
    mfma(Xb_h, Xb_l, 7, nn2_b[3], 0, outp, 12, nullptr, nullptr, 0, 0);

    // ---- nn3: cat(x,preds_id)=18 -> 256 -> 256 -> 256 -> 6 (d_out cols 6..11)
    cat3_pack<<<M * 4 / 256, 256, 0, stream>>>(x, outp, Xa_h, Xa_l);
    mfma(Xa_h, Xa_l, 8, nn3_b[0], 1, nullptr, 0, Xb_h, Xb_l, 256, 256);
    mfma(Xb_h, Xb_l, 9, nn3_b[1], 1, nullptr, 0, Xa_h, Xa_l, 256, 256);
    mfma(Xa_h, Xa_l, 10, nn3_b[2], 1, nullptr, 0, Xb_h, Xb_l, 256, 256);
    mfma(Xb_h, Xb_l, 11, nn3_b[3], 0, outp + 6, 12, nullptr, nullptr, 0, 0);
}